// Round 2
// baseline (204.182 us; speedup 1.0000x reference)
//
#include <hip/hip_runtime.h>
#include <hip/hip_bf16.h>

// VQVAE quantize.  x: [8,64,32,32] fp32, codebook: [8192,64] fp32.
// d_out (fp32, concat): [0,524288) quant_out | [524288] commit_loss |
//                       [524289] codebook_loss | [524290,532482) indices
//
// argmin_k over key = e2[k] - 2*dot(x_n,e_k)   (x2[n] is a per-point constant:
// dropping it does not change the exact comparison; round-1 absmax was 0.0).

#define N_PTS   8192
#define K_CODES 8192
#define C_DIM   64
#define HWSZ    1024
#define QOUT_N  524288

// ---- workspace layout (bytes) ----
#define WS_CBT   0            // float [64][8192]  = 2097152 B
#define WS_E2    2097152      // float [8192]      = 32768 B
#define WS_PACK  2129920      // u64   [8192]      = 65536 B
#define WS_LOSS  2195456      // float [1]

// ============================================================
// Kernel A: prep. 128 blocks x 256. 4 threads per codebook row:
// thread (k, q) loads cb[k][q*16..q*16+15], writes cbT, shuffle-
// reduces e2. Also inits packed[] and lossAcc.
// ============================================================
__global__ __launch_bounds__(256)
void vq_prep_kernel(const float* __restrict__ cb,
                    float* __restrict__ cbT,
                    float* __restrict__ e2,
                    unsigned long long* __restrict__ packed,
                    float* __restrict__ lossAcc)
{
    const int t = blockIdx.x * 256 + threadIdx.x;   // 0..32767
    const int k = t >> 2;
    const int q = t & 3;

    float s = 0.0f;
    #pragma unroll
    for (int j = 0; j < 4; ++j) {
        float4 v = *(const float4*)(cb + k * C_DIM + q * 16 + j * 4);
        s += v.x * v.x + v.y * v.y + v.z * v.z + v.w * v.w;
        const int c = q * 16 + j * 4;
        cbT[(c + 0) * K_CODES + k] = v.x;
        cbT[(c + 1) * K_CODES + k] = v.y;
        cbT[(c + 2) * K_CODES + k] = v.z;
        cbT[(c + 3) * K_CODES + k] = v.w;
    }
    // reduce e2 over the 4 q-lanes (consecutive lanes in the wave)
    s += __shfl_xor(s, 1, 64);
    s += __shfl_xor(s, 2, 64);
    if (q == 0) e2[k] = s;

    if (t < N_PTS) packed[t] = ~0ull;
    if (t == 0) *lossAcc = 0.0f;
}

// ============================================================
// Kernel B: argmin GEMM. grid (64 m-tiles, 8 k-splits), 256 thr.
// Block: 128 pts x 1024 codes (8 chunks of 128). Thread (ty,tx):
//   m = ty*8 + {0..7},  k = tx*4+{0..3} and 64+tx*4+{0..3}.
// cs reads: 16 contiguous 16B chunks across tx -> 2-way bank
// aliasing only (free). xs reads: 4 distinct 32B rows per wave,
// 16-way broadcast, disjoint bank octets (free).
// Next cs chunk prefetched global->reg during the FMA loop.
// ============================================================
#define BM 128
#define BK 128
#define SPLITS 8
#define CHUNKS 8

__global__ __launch_bounds__(256, 2)
void vq_argmin_kernel(const float* __restrict__ x,     // [8][64][1024]
                      const float* __restrict__ cbT,   // [64][8192]
                      const float* __restrict__ e2,    // [8192]
                      unsigned long long* __restrict__ packed)
{
    __shared__ float xs[C_DIM][BM];   // 32 KB
    __shared__ float cs[C_DIM][BK];   // 32 KB

    const int tid = threadIdx.x;
    const int tx  = tid & 15;
    const int ty  = tid >> 4;
    const int mt    = blockIdx.x;
    const int split = blockIdx.y;
    const int n0  = mt * BM;
    const int b   = mt >> 3;
    const int hw0 = (mt & 7) * BM;
    const float* xbase = x + b * (C_DIM * HWSZ) + hw0;

    // stage xs (reused by all chunks): coalesced, contiguous LDS b128
    #pragma unroll
    for (int i = 0; i < 8; ++i) {
        int f  = tid + i * 256;
        int c  = f >> 5;
        int m4 = (f & 31) << 2;
        *(float4*)&xs[c][m4] = *(const float4*)(xbase + c * HWSZ + m4);
    }

    // stage chunk 0 of cs
    const int kbase = split * (CHUNKS * BK);
    float4 pf[8];
    #pragma unroll
    for (int i = 0; i < 8; ++i) {
        int f  = tid + i * 256;
        int c  = f >> 5;
        int k4 = (f & 31) << 2;
        pf[i] = *(const float4*)(cbT + c * K_CODES + kbase + k4);
    }
    #pragma unroll
    for (int i = 0; i < 8; ++i) {
        int f  = tid + i * 256;
        int c  = f >> 5;
        int k4 = (f & 31) << 2;
        *(float4*)&cs[c][k4] = pf[i];
    }
    __syncthreads();

    unsigned long long best[8];
    #pragma unroll
    for (int mi = 0; mi < 8; ++mi) best[mi] = ~0ull;

    for (int ch = 0; ch < CHUNKS; ++ch) {
        const int k0 = kbase + ch * BK;

        // prefetch next chunk into registers (latency hidden by FMAs)
        if (ch + 1 < CHUNKS) {
            #pragma unroll
            for (int i = 0; i < 8; ++i) {
                int f  = tid + i * 256;
                int c  = f >> 5;
                int k4 = (f & 31) << 2;
                pf[i] = *(const float4*)(cbT + c * K_CODES + k0 + BK + k4);
            }
        }

        float acc[8][8];
        #pragma unroll
        for (int mi = 0; mi < 8; ++mi)
            #pragma unroll
            for (int ki = 0; ki < 8; ++ki) acc[mi][ki] = 0.0f;

        #pragma unroll 4
        for (int c = 0; c < C_DIM; ++c) {
            float4 xq0 = *(const float4*)&xs[c][ty * 8];
            float4 xq1 = *(const float4*)&xs[c][ty * 8 + 4];
            float4 cq0 = *(const float4*)&cs[c][tx * 4];
            float4 cq1 = *(const float4*)&cs[c][64 + tx * 4];
            float xv[8] = {xq0.x, xq0.y, xq0.z, xq0.w, xq1.x, xq1.y, xq1.z, xq1.w};
            float cv[8] = {cq0.x, cq0.y, cq0.z, cq0.w, cq1.x, cq1.y, cq1.z, cq1.w};
            #pragma unroll
            for (int mi = 0; mi < 8; ++mi)
                #pragma unroll
                for (int ki = 0; ki < 8; ++ki)
                    acc[mi][ki] = fmaf(xv[mi], cv[ki], acc[mi][ki]);
        }

        // epilogue: key = e2[k] - 2*dot; float-min first, one u64 pack per mi
        float e2a[8];
        *(float4*)&e2a[0] = *(const float4*)(e2 + k0 + tx * 4);
        *(float4*)&e2a[4] = *(const float4*)(e2 + k0 + 64 + tx * 4);
        #pragma unroll
        for (int mi = 0; mi < 8; ++mi) {
            float dmin;
            #pragma unroll
            for (int ki = 0; ki < 8; ++ki) {
                float d = fmaf(-2.0f, acc[mi][ki], e2a[ki]);
                acc[mi][ki] = d;
                dmin = (ki == 0) ? d : fminf(dmin, d);
            }
            int sel = 0;
            #pragma unroll
            for (int ki = 7; ki >= 0; --ki)
                sel = (acc[mi][ki] == dmin) ? ki : sel;   // smallest ki on tie
            unsigned kk = (unsigned)(k0 + tx * 4 + sel + ((sel >> 2) * 60));
            unsigned u = __float_as_uint(dmin);
            u ^= ((unsigned)((int)u >> 31)) | 0x80000000u;  // order-preserving flip
            unsigned long long p = ((unsigned long long)u << 32) | kk;
            best[mi] = (p < best[mi]) ? p : best[mi];
        }

        __syncthreads();                 // all waves done reading cs
        if (ch + 1 < CHUNKS) {
            #pragma unroll
            for (int i = 0; i < 8; ++i) {
                int f  = tid + i * 256;
                int c  = f >> 5;
                int k4 = (f & 31) << 2;
                *(float4*)&cs[c][k4] = pf[i];
            }
        }
        __syncthreads();                 // cs chunk visible
    }

    // block reduce across the 16 tx candidates per point, one atomic/pt
    unsigned long long* sred = (unsigned long long*)&xs[0][0]; // 128*17*8 B
    #pragma unroll
    for (int mi = 0; mi < 8; ++mi)
        sred[(ty * 8 + mi) * 17 + tx] = best[mi];
    __syncthreads();
    if (tid < BM) {
        unsigned long long v = sred[tid * 17];
        #pragma unroll
        for (int t = 1; t < 16; ++t) {
            unsigned long long w = sred[tid * 17 + t];
            v = (w < v) ? w : v;
        }
        atomicMin(packed + n0 + tid, v);
    }
}

// ============================================================
// Kernel C: gather. 64 blocks x 256; 2 threads per point, each
// owns a 32-channel half. Lanes are hw-contiguous -> coalesced.
// ============================================================
__global__ __launch_bounds__(256)
void vq_gather_kernel(const float* __restrict__ x,
                      const float* __restrict__ cb,
                      const unsigned long long* __restrict__ packed,
                      float* __restrict__ out,
                      float* __restrict__ lossAcc)
{
    const int t = blockIdx.x * 256 + threadIdx.x;   // 0..16383
    const int n    = t & (N_PTS - 1);
    const int half = t >> 13;
    const int c0   = half * 32;
    const unsigned idx = (unsigned)(packed[n] & 0xFFFFFFFFull);
    const int b  = n >> 10;
    const int hw = n & 1023;
    const float* xb = x   + b * (C_DIM * HWSZ) + hw;
    float*       ob = out + b * (C_DIM * HWSZ) + hw;

    float s = 0.0f;
    #pragma unroll
    for (int c4 = 0; c4 < 8; ++c4) {
        float4 q = *(const float4*)(cb + (size_t)idx * C_DIM + c0 + c4 * 4);
        float qa[4] = {q.x, q.y, q.z, q.w};
        #pragma unroll
        for (int j = 0; j < 4; ++j) {
            int c = c0 + c4 * 4 + j;
            float xv = xb[c * HWSZ];
            float d  = qa[j] - xv;          // quant - x (reference rounding)
            s = fmaf(d, d, s);
            ob[c * HWSZ] = xv + d;          // straight-through: x + (q - x)
        }
    }

    if (half == 0) out[QOUT_N + 2 + n] = (float)idx;

    #pragma unroll
    for (int off = 32; off > 0; off >>= 1) s += __shfl_down(s, off, 64);
    if ((threadIdx.x & 63) == 0) atomicAdd(lossAcc, s);
}

// ============================================================
// Kernel D: finalize the two loss scalars.
// ============================================================
__global__ void vq_final_kernel(const float* __restrict__ lossAcc,
                                float* __restrict__ out)
{
    float m = *lossAcc * (1.0f / (float)QOUT_N);
    out[QOUT_N]     = m;   // commitment_loss
    out[QOUT_N + 1] = m;   // codebook_loss
}

extern "C" void kernel_launch(void* const* d_in, const int* in_sizes, int n_in,
                              void* d_out, int out_size, void* d_ws, size_t ws_size,
                              hipStream_t stream)
{
    const float* x  = (const float*)d_in[0];   // [8,64,32,32]
    const float* cb = (const float*)d_in[1];   // [8192,64]
    float* out = (float*)d_out;
    char*  ws  = (char*)d_ws;

    float* cbT = (float*)(ws + WS_CBT);
    float* e2  = (float*)(ws + WS_E2);
    unsigned long long* packed = (unsigned long long*)(ws + WS_PACK);
    float* lossAcc = (float*)(ws + WS_LOSS);

    vq_prep_kernel<<<128, 256, 0, stream>>>(cb, cbT, e2, packed, lossAcc);
    vq_argmin_kernel<<<dim3(N_PTS / BM, SPLITS), 256, 0, stream>>>(x, cbT, e2, packed);
    vq_gather_kernel<<<64, 256, 0, stream>>>(x, cb, packed, out, lossAcc);
    vq_final_kernel<<<1, 1, 0, stream>>>(lossAcc, out);
}

// Round 3
// 185.875 us; speedup vs baseline: 1.0985x; 1.0985x over previous
//
#include <hip/hip_runtime.h>

// VQVAE quantize.  x: [8,64,32,32] fp32, codebook: [8192,64] fp32.
// d_out (fp32, concat): [0,524288) quant_out | [524288] commit_loss |
//                       [524289] codebook_loss | [524290,532482) indices
//
// argmin_k of key = 0.5*e2[k] - dot(x_n, e_k)   (monotone in the true d2;
// x2[n] is a per-point constant, 0.5 scale is exact).

#define N_PTS   8192
#define K_CODES 8192
#define C_DIM   64
#define HWSZ    1024
#define QOUT_N  524288

// ---- workspace layout (bytes) ----
#define WS_CBT   0            // float [64][8192]        = 2097152
#define WS_E2H   2097152      // float [8192] (0.5*e2)   = 32768
#define WS_PACK  2129920      // u64 [8][8192]           = 524288
#define WS_PART  2654208      // float [256] loss partials

#define BM 128
#define BK 128
#define CHUNKS 8
#define SPLITS 8

// async 16B global -> LDS (wave-uniform base + lane*16; our patterns comply)
__device__ __forceinline__ void cp16(const float* g, float* l) {
    __builtin_amdgcn_global_load_lds(
        (const __attribute__((address_space(1))) void*)g,
        (__attribute__((address_space(3))) void*)l, 16, 0, 0);
}

// ============================================================
// Kernel A: prep. 128 blocks x 256. LDS-tile transpose of the
// codebook (64 rows/block) + e2h. Coalesced global both ways,
// <=2-way LDS bank aliasing both ways (stride-65 scalar tile).
// ============================================================
__global__ __launch_bounds__(256)
void vq_prep_kernel(const float* __restrict__ cb,
                    float* __restrict__ cbT,
                    float* __restrict__ e2h)
{
    __shared__ __align__(16) float t[64][65];
    const int tid = threadIdx.x;
    const int kb  = blockIdx.x * 64;

    #pragma unroll
    for (int i = 0; i < 4; ++i) {
        int f  = tid + i * 256;            // 0..1023
        int r  = f >> 4;
        int c4 = (f & 15) << 2;
        float4 v = *(const float4*)(cb + (kb + r) * C_DIM + c4);
        t[r][c4 + 0] = v.x; t[r][c4 + 1] = v.y;
        t[r][c4 + 2] = v.z; t[r][c4 + 3] = v.w;
    }
    __syncthreads();

    if (tid < 64) {
        float s = 0.0f;
        #pragma unroll 16
        for (int c = 0; c < C_DIM; ++c) { float v = t[tid][c]; s = fmaf(v, v, s); }
        e2h[kb + tid] = 0.5f * s;
    }

    #pragma unroll
    for (int i = 0; i < 4; ++i) {
        int f  = tid + i * 256;            // 0..1023
        int c  = f >> 4;
        int kk = (f & 15) << 2;
        float4 v;
        v.x = t[kk + 0][c]; v.y = t[kk + 1][c];
        v.z = t[kk + 2][c]; v.w = t[kk + 3][c];
        *(float4*)(cbT + c * K_CODES + kb + kk) = v;
    }
}

// ============================================================
// Kernel B: argmin GEMM. grid (64 m-tiles, 8 splits), 256 thr.
// 128 pts x 1024 codes per block (8 chunks of 128). Thread
// (ty,tx): m = ty*8+{0..7}, k = tx*4+{0..3} and 64+tx*4+{0..3}.
// All staging via async global_load_lds (no staging VGPRs).
// e2h chunk slice lives in cs row 64. Per-split result slots ->
// plain stores, no atomics, no init.
// ============================================================
__global__ __launch_bounds__(256, 2)
void vq_argmin_kernel(const float* __restrict__ x,     // [8][64][1024]
                      const float* __restrict__ cbT,   // [64][8192]
                      const float* __restrict__ e2h,   // [8192]
                      unsigned long long* __restrict__ packedS) // [8][8192]
{
    __shared__ __align__(16) float xs[C_DIM][BM];       // 32 KB
    __shared__ __align__(16) float cs[C_DIM + 1][BK];   // 33.3 KB (+e2 row)

    const int tid = threadIdx.x;
    const int tx  = tid & 15;
    const int ty  = tid >> 4;
    const int mt    = blockIdx.x;
    const int split = blockIdx.y;
    const int n0  = mt * BM;
    const int b   = mt >> 3;
    const int hw0 = (mt & 7) * BM;
    const float* xbase = x + b * (C_DIM * HWSZ) + hw0;
    const int kbase = split * (CHUNKS * BK);

    // async stage: xs (whole block lifetime), cs chunk 0, e2 slice 0
    #pragma unroll
    for (int i = 0; i < 8; ++i) {
        int f = tid + i * 256;
        int c = f >> 5;
        int m4 = (f & 31) << 2;
        cp16(xbase + c * HWSZ + m4, &xs[c][m4]);
    }
    #pragma unroll
    for (int i = 0; i < 8; ++i) {
        int f = tid + i * 256;
        int c = f >> 5;
        int k4 = (f & 31) << 2;
        cp16(cbT + c * K_CODES + kbase + k4, &cs[c][k4]);
    }
    if (tid < 32) cp16(e2h + kbase + tid * 4, &cs[C_DIM][tid * 4]);
    __syncthreads();   // vmcnt(0) drained before barrier -> LDS ready

    unsigned long long best[8];
    #pragma unroll
    for (int mi = 0; mi < 8; ++mi) best[mi] = ~0ull;

    for (int ch = 0; ch < CHUNKS; ++ch) {
        const int k0 = kbase + ch * BK;

        // acc init = 0.5*e2[k]  (from LDS e2 row)
        float4 ea = *(const float4*)&cs[C_DIM][tx * 4];
        float4 eb = *(const float4*)&cs[C_DIM][64 + tx * 4];
        float acc[8][8];
        #pragma unroll
        for (int mi = 0; mi < 8; ++mi) {
            acc[mi][0] = ea.x; acc[mi][1] = ea.y; acc[mi][2] = ea.z; acc[mi][3] = ea.w;
            acc[mi][4] = eb.x; acc[mi][5] = eb.y; acc[mi][6] = eb.z; acc[mi][7] = eb.w;
        }

        #pragma unroll 4
        for (int c = 0; c < C_DIM; ++c) {
            float4 xa  = *(const float4*)&xs[c][ty * 8];
            float4 xb  = *(const float4*)&xs[c][ty * 8 + 4];
            float4 ca  = *(const float4*)&cs[c][tx * 4];
            float4 cb2 = *(const float4*)&cs[c][64 + tx * 4];
            float xv[8] = {xa.x, xa.y, xa.z, xa.w, xb.x, xb.y, xb.z, xb.w};
            float cv[8] = {ca.x, ca.y, ca.z, ca.w, cb2.x, cb2.y, cb2.z, cb2.w};
            #pragma unroll
            for (int mi = 0; mi < 8; ++mi)
                #pragma unroll
                for (int ki = 0; ki < 8; ++ki)
                    acc[mi][ki] = fmaf(-xv[mi], cv[ki], acc[mi][ki]);  // key accum
        }

        // epilogue: min + pack (key ascending == distance ascending)
        #pragma unroll
        for (int mi = 0; mi < 8; ++mi) {
            float dmin = acc[mi][0];
            #pragma unroll
            for (int ki = 1; ki < 8; ++ki) dmin = fminf(dmin, acc[mi][ki]);
            int sel = 0;
            #pragma unroll
            for (int ki = 7; ki >= 0; --ki)
                sel = (acc[mi][ki] == dmin) ? ki : sel;   // smallest ki on tie
            unsigned kk = (unsigned)(k0 + tx * 4 + sel + ((sel >> 2) * 60));
            unsigned u = __float_as_uint(dmin);
            u ^= ((unsigned)((int)u >> 31)) | 0x80000000u;
            unsigned long long p = ((unsigned long long)u << 32) | kk;
            best[mi] = (p < best[mi]) ? p : best[mi];
        }

        __syncthreads();              // everyone done reading cs
        if (ch + 1 < CHUNKS) {        // async stage next chunk
            #pragma unroll
            for (int i = 0; i < 8; ++i) {
                int f = tid + i * 256;
                int c = f >> 5;
                int k4 = (f & 31) << 2;
                cp16(cbT + c * K_CODES + k0 + BK + k4, &cs[c][k4]);
            }
            if (tid < 32) cp16(e2h + k0 + BK + tid * 4, &cs[C_DIM][tid * 4]);
        }
        __syncthreads();              // staged chunk visible
    }

    // block reduce the 16 tx candidates per point; plain store (owned slot)
    unsigned long long* sred = (unsigned long long*)&xs[0][0]; // 128*17*8 B
    #pragma unroll
    for (int mi = 0; mi < 8; ++mi)
        sred[(ty * 8 + mi) * 17 + tx] = best[mi];
    __syncthreads();
    if (tid < BM) {
        unsigned long long v = sred[tid * 17];
        #pragma unroll
        for (int t = 1; t < 16; ++t) {
            unsigned long long w = sred[tid * 17 + t];
            v = (w < v) ? w : v;
        }
        packedS[split * N_PTS + n0 + tid] = v;
    }
}

// ============================================================
// Kernel C: gather. 64 blocks x 256; 2 threads per point (32-ch
// halves). Reduces the 8 split slots, writes quant_out/indices,
// per-wave loss partials to owned slots (no atomics).
// ============================================================
__global__ __launch_bounds__(256)
void vq_gather_kernel(const float* __restrict__ x,
                      const float* __restrict__ cb,
                      const unsigned long long* __restrict__ packedS,
                      float* __restrict__ out,
                      float* __restrict__ part)
{
    const int t = blockIdx.x * 256 + threadIdx.x;   // 0..16383
    const int n    = t & (N_PTS - 1);
    const int half = t >> 13;
    const int c0   = half * 32;

    unsigned long long v = packedS[n];
    #pragma unroll
    for (int s = 1; s < SPLITS; ++s) {
        unsigned long long w = packedS[s * N_PTS + n];
        v = (w < v) ? w : v;
    }
    const unsigned idx = (unsigned)(v & 0xFFFFFFFFull);

    const int b  = n >> 10;
    const int hw = n & 1023;
    const float* xb = x   + b * (C_DIM * HWSZ) + hw;
    float*       ob = out + b * (C_DIM * HWSZ) + hw;

    float s = 0.0f;
    #pragma unroll
    for (int c4 = 0; c4 < 8; ++c4) {
        float4 q = *(const float4*)(cb + (size_t)idx * C_DIM + c0 + c4 * 4);
        float qa[4] = {q.x, q.y, q.z, q.w};
        #pragma unroll
        for (int j = 0; j < 4; ++j) {
            int c = c0 + c4 * 4 + j;
            float xv = xb[c * HWSZ];
            float d  = qa[j] - xv;          // quant - x (reference rounding)
            s = fmaf(d, d, s);
            ob[c * HWSZ] = xv + d;          // straight-through: x + (q - x)
        }
    }

    if (half == 0) out[QOUT_N + 2 + n] = (float)idx;

    #pragma unroll
    for (int off = 32; off > 0; off >>= 1) s += __shfl_down(s, off, 64);
    if ((threadIdx.x & 63) == 0) part[t >> 6] = s;
}

// ============================================================
// Kernel D: final loss reduction (256 partials -> 2 scalars).
// ============================================================
__global__ __launch_bounds__(256)
void vq_final_kernel(const float* __restrict__ part, float* __restrict__ out)
{
    __shared__ float w[4];
    float s = part[threadIdx.x];
    #pragma unroll
    for (int off = 32; off > 0; off >>= 1) s += __shfl_down(s, off, 64);
    if ((threadIdx.x & 63) == 0) w[threadIdx.x >> 6] = s;
    __syncthreads();
    if (threadIdx.x == 0) {
        float m = (w[0] + w[1] + w[2] + w[3]) * (1.0f / (float)QOUT_N);
        out[QOUT_N]     = m;   // commitment_loss
        out[QOUT_N + 1] = m;   // codebook_loss
    }
}

extern "C" void kernel_launch(void* const* d_in, const int* in_sizes, int n_in,
                              void* d_out, int out_size, void* d_ws, size_t ws_size,
                              hipStream_t stream)
{
    const float* x  = (const float*)d_in[0];   // [8,64,32,32]
    const float* cb = (const float*)d_in[1];   // [8192,64]
    float* out = (float*)d_out;
    char*  ws  = (char*)d_ws;

    float* cbT = (float*)(ws + WS_CBT);
    float* e2h = (float*)(ws + WS_E2H);
    unsigned long long* packedS = (unsigned long long*)(ws + WS_PACK);
    float* part = (float*)(ws + WS_PART);

    vq_prep_kernel<<<128, 256, 0, stream>>>(cb, cbT, e2h);
    vq_argmin_kernel<<<dim3(N_PTS / BM, SPLITS), 256, 0, stream>>>(x, cbT, e2h, packedS);
    vq_gather_kernel<<<64, 256, 0, stream>>>(x, cb, packedS, out, part);
    vq_final_kernel<<<1, 256, 0, stream>>>(part, out);
}

// Round 4
// 116.293 us; speedup vs baseline: 1.7558x; 1.5983x over previous
//
#include <hip/hip_runtime.h>

// VQVAE quantize.  x: [8,64,32,32] fp32, codebook: [8192,64] fp32.
// d_out (fp32, concat): [0,524288) quant_out | [524288] commit_loss |
//                       [524289] codebook_loss | [524290,532482) indices
//
// argmin via bf16x3 emulated-fp32 MFMA GEMM:
//   v = h + m + l (3 bf16, exact to 2^-27); dot = hh+hm+mh+hl+lh+mm
//   key = 0.5*e2[k] - dot  (monotone in d2; error ~3e-6 << top-2 gap ~3.5)

#define N_PTS   8192
#define K_CODES 8192
#define C_DIM   64
#define HWSZ    1024
#define QOUT_N  524288
#define SPLITS  16            // codes per split = 512

// ---- workspace layout (bytes) ----
#define WS_XS    0            // u16 [3][8][8192][8]  = 3145728
#define WS_CBS   3145728      // u16 [3][8][8192][8]  = 3145728
#define WS_E2H   6291456      // float [8192]         = 32768
#define WS_PACK  6324224      // u64 [16][8192]       = 1048576
#define WS_PART  7372800      // float [256]

typedef __attribute__((ext_vector_type(8))) short short8;
typedef __attribute__((ext_vector_type(4))) float floatx4;

__device__ __forceinline__ unsigned short bf16_rne(float f) {
    unsigned u = __float_as_uint(f);
    return (unsigned short)((u + 0x7FFFu + ((u >> 16) & 1u)) >> 16);
}
__device__ __forceinline__ float bf16_val(unsigned short h) {
    return __uint_as_float(((unsigned)h) << 16);
}

// ============================================================
// Kernel A: prep. 160 blocks x 256.
//  blocks 0..63   : x split   (b = bx>>3, g = bx&7)
//  blocks 64..127 : cb split  (g = (bx-64)>>3, kchunk = (bx-64)&7)
//  blocks 128..159: e2h
// Planes laid out [p][g][n][8]: per (point|code), the 8 channels of
// c-octet g are contiguous (16 B) == one MFMA fragment k-group.
// ============================================================
__global__ __launch_bounds__(256)
void vq_prep_kernel(const float* __restrict__ x,
                    const float* __restrict__ cb,
                    unsigned short* __restrict__ xS,
                    unsigned short* __restrict__ cbS,
                    float* __restrict__ e2h)
{
    const int bx  = blockIdx.x;
    const int tid = threadIdx.x;

    if (bx >= 128) {                         // ---- e2h ----
        int k = (bx - 128) * 256 + tid;
        float s = 0.0f;
        #pragma unroll
        for (int j = 0; j < 16; ++j) {
            float4 v = *(const float4*)(cb + k * C_DIM + j * 4);
            s += v.x * v.x + v.y * v.y + v.z * v.z + v.w * v.w;
        }
        e2h[k] = 0.5f * s;
        return;
    }

    __shared__ unsigned short sp[3][1024][8];
    unsigned short* outp;
    if (bx < 64) {                           // ---- x split ----
        const int b = bx >> 3, g = bx & 7;
        #pragma unroll
        for (int cq = 0; cq < 8; ++cq) {     // channel within octet
            int c = g * 8 + cq;
            float4 v = *(const float4*)(x + (b * C_DIM + c) * HWSZ + tid * 4);
            float vv[4] = {v.x, v.y, v.z, v.w};
            #pragma unroll
            for (int j = 0; j < 4; ++j) {
                int n = tid * 4 + j;
                unsigned short h = bf16_rne(vv[j]);
                float r1 = vv[j] - bf16_val(h);
                unsigned short m = bf16_rne(r1);
                float r2 = r1 - bf16_val(m);
                unsigned short l = bf16_rne(r2);
                sp[0][n][cq] = h; sp[1][n][cq] = m; sp[2][n][cq] = l;
            }
        }
        outp = xS + ((size_t)g * 8192 + b * 1024) * 8;
    } else {                                 // ---- cb split ----
        const int u = bx - 64, g = u >> 3, kc = u & 7;
        const int k0 = kc * 1024;
        #pragma unroll
        for (int i = 0; i < 4; ++i) {
            int kk = tid + i * 256;          // 0..1023
            const float* row = cb + (k0 + kk) * C_DIM + g * 8;
            float4 va = *(const float4*)(row);
            float4 vb = *(const float4*)(row + 4);
            float vv[8] = {va.x, va.y, va.z, va.w, vb.x, vb.y, vb.z, vb.w};
            #pragma unroll
            for (int j = 0; j < 8; ++j) {
                unsigned short h = bf16_rne(vv[j]);
                float r1 = vv[j] - bf16_val(h);
                unsigned short m = bf16_rne(r1);
                float r2 = r1 - bf16_val(m);
                unsigned short l = bf16_rne(r2);
                sp[0][kk][j] = h; sp[1][kk][j] = m; sp[2][kk][j] = l;
            }
        }
        outp = cbS + ((size_t)g * 8192 + k0) * 8;
    }
    __syncthreads();
    // coalesced write-out: per plane 1024 rows x 16 B
    #pragma unroll
    for (int p = 0; p < 3; ++p)
        #pragma unroll
        for (int i = 0; i < 4; ++i) {
            int n = tid + i * 256;
            *(uint4*)(outp + ((size_t)p * 8 * 8192 + n) * 8) = *(const uint4*)&sp[p][n][0];
        }
}

// ============================================================
// Kernel B: argmin via MFMA. grid (32 m-blocks, 16 splits), 256 thr.
// Wave owns 64 points (4 tiles of 16); A-frags (h,m,l x 2 ksteps)
// resident in regs. Loop over 32 N-tiles of 16 codes: B-frags
// direct from global (L2), 48 MFMA (6 terms x 2 ksteps x 4 tiles),
// branchless running (key,idx). Final 16-col reduce through LDS.
// Layouts (verified m89/m91/m120): A[m=lane&15][k=quad*8+j],
// B[k=quad*8+j][n=lane&15], C: col=lane&15, row=quad*4+reg.
// ============================================================
__global__ __launch_bounds__(256, 2)
void vq_argmin_kernel(const unsigned short* __restrict__ xS,
                      const unsigned short* __restrict__ cbS,
                      const float* __restrict__ e2h,
                      unsigned long long* __restrict__ packedS)
{
    __shared__ unsigned long long red[256][17];
    const int tid   = threadIdx.x;
    const int lane  = tid & 63;
    const int w     = tid >> 6;
    const int col   = lane & 15;
    const int quad  = lane >> 4;
    const int mb    = blockIdx.x;
    const int split = blockIdx.y;
    const int m0    = mb * 256 + w * 64;
    const int nb0   = split * 512;

    // A fragments: 4 tiles x 3 planes x 2 ksteps (96 VGPRs)
    short8 af[4][3][2];
    #pragma unroll
    for (int t = 0; t < 4; ++t) {
        int pt = m0 + t * 16 + col;
        #pragma unroll
        for (int p = 0; p < 3; ++p)
            #pragma unroll
            for (int s = 0; s < 2; ++s) {
                int g = s * 4 + quad;
                af[t][p][s] = *(const short8*)(xS + ((p * 8 + g) * 8192 + pt) * 8);
            }
    }

    float bestk[4][4];
    int   besti[4][4];
    #pragma unroll
    for (int t = 0; t < 4; ++t)
        #pragma unroll
        for (int r = 0; r < 4; ++r) {
            bestk[t][r] = __uint_as_float(0x7F800000u);  // +inf
            besti[t][r] = 0;
        }

    for (int nt = 0; nt < 32; ++nt) {
        const int code = nb0 + nt * 16 + col;

        short8 bf[3][2];
        #pragma unroll
        for (int p = 0; p < 3; ++p)
            #pragma unroll
            for (int s = 0; s < 2; ++s) {
                int g = s * 4 + quad;
                bf[p][s] = *(const short8*)(cbS + ((p * 8 + g) * 8192 + code) * 8);
            }
        const float e2v = e2h[code];

        floatx4 acc[4];
        #pragma unroll
        for (int t = 0; t < 4; ++t) acc[t] = (floatx4){0.f, 0.f, 0.f, 0.f};

        #pragma unroll
        for (int s = 0; s < 2; ++s) {
            #pragma unroll
            for (int t = 0; t < 4; ++t)
                acc[t] = __builtin_amdgcn_mfma_f32_16x16x32_bf16(af[t][0][s], bf[0][s], acc[t], 0, 0, 0); // hh
            #pragma unroll
            for (int t = 0; t < 4; ++t)
                acc[t] = __builtin_amdgcn_mfma_f32_16x16x32_bf16(af[t][0][s], bf[1][s], acc[t], 0, 0, 0); // hm
            #pragma unroll
            for (int t = 0; t < 4; ++t)
                acc[t] = __builtin_amdgcn_mfma_f32_16x16x32_bf16(af[t][1][s], bf[0][s], acc[t], 0, 0, 0); // mh
            #pragma unroll
            for (int t = 0; t < 4; ++t)
                acc[t] = __builtin_amdgcn_mfma_f32_16x16x32_bf16(af[t][0][s], bf[2][s], acc[t], 0, 0, 0); // hl
            #pragma unroll
            for (int t = 0; t < 4; ++t)
                acc[t] = __builtin_amdgcn_mfma_f32_16x16x32_bf16(af[t][2][s], bf[0][s], acc[t], 0, 0, 0); // lh
            #pragma unroll
            for (int t = 0; t < 4; ++t)
                acc[t] = __builtin_amdgcn_mfma_f32_16x16x32_bf16(af[t][1][s], bf[1][s], acc[t], 0, 0, 0); // mm
        }

        #pragma unroll
        for (int t = 0; t < 4; ++t)
            #pragma unroll
            for (int r = 0; r < 4; ++r) {
                float key = e2v - acc[t][r];
                bool lt = key < bestk[t][r];     // strict: earlier code wins ties
                bestk[t][r] = lt ? key  : bestk[t][r];
                besti[t][r] = lt ? code : besti[t][r];
            }
    }

    // pack + cross-col reduce via LDS
    #pragma unroll
    for (int t = 0; t < 4; ++t)
        #pragma unroll
        for (int r = 0; r < 4; ++r) {
            unsigned u = __float_as_uint(bestk[t][r]);
            u = ((int)u < 0) ? ~u : (u | 0x80000000u);
            unsigned long long p = ((unsigned long long)u << 32) | (unsigned)besti[t][r];
            red[w * 64 + t * 16 + quad * 4 + r][col] = p;
        }
    __syncthreads();
    unsigned long long v = red[tid][0];
    #pragma unroll
    for (int c = 1; c < 16; ++c) {
        unsigned long long q = red[tid][c];
        v = (q < v) ? q : v;
    }
    packedS[split * N_PTS + mb * 256 + tid] = v;
}

// ============================================================
// Kernel C: gather. 64 blocks x 256; 2 threads per point (32-ch
// halves). Reduce the 16 split slots, write quant_out/indices,
// per-wave loss partials (no atomics).
// ============================================================
__global__ __launch_bounds__(256)
void vq_gather_kernel(const float* __restrict__ x,
                      const float* __restrict__ cb,
                      const unsigned long long* __restrict__ packedS,
                      float* __restrict__ out,
                      float* __restrict__ part)
{
    const int t = blockIdx.x * 256 + threadIdx.x;   // 0..16383
    const int n    = t & (N_PTS - 1);
    const int half = t >> 13;
    const int c0   = half * 32;

    unsigned long long v = packedS[n];
    #pragma unroll
    for (int s = 1; s < SPLITS; ++s) {
        unsigned long long q = packedS[s * N_PTS + n];
        v = (q < v) ? q : v;
    }
    const unsigned idx = (unsigned)(v & 0xFFFFFFFFull);

    const int b  = n >> 10;
    const int hw = n & 1023;
    const float* xb = x   + b * (C_DIM * HWSZ) + hw;
    float*       ob = out + b * (C_DIM * HWSZ) + hw;

    float s = 0.0f;
    #pragma unroll
    for (int c4 = 0; c4 < 8; ++c4) {
        float4 q = *(const float4*)(cb + (size_t)idx * C_DIM + c0 + c4 * 4);
        float qa[4] = {q.x, q.y, q.z, q.w};
        #pragma unroll
        for (int j = 0; j < 4; ++j) {
            int c = c0 + c4 * 4 + j;
            float xv = xb[c * HWSZ];
            float d  = qa[j] - xv;          // quant - x (reference rounding)
            s = fmaf(d, d, s);
            ob[c * HWSZ] = xv + d;          // straight-through: x + (q - x)
        }
    }

    if (half == 0) out[QOUT_N + 2 + n] = (float)idx;

    #pragma unroll
    for (int off = 32; off > 0; off >>= 1) s += __shfl_down(s, off, 64);
    if ((threadIdx.x & 63) == 0) part[t >> 6] = s;
}

// ============================================================
// Kernel D: final loss reduction (256 partials -> 2 scalars).
// ============================================================
__global__ __launch_bounds__(256)
void vq_final_kernel(const float* __restrict__ part, float* __restrict__ out)
{
    __shared__ float w[4];
    float s = part[threadIdx.x];
    #pragma unroll
    for (int off = 32; off > 0; off >>= 1) s += __shfl_down(s, off, 64);
    if ((threadIdx.x & 63) == 0) w[threadIdx.x >> 6] = s;
    __syncthreads();
    if (threadIdx.x == 0) {
        float m = (w[0] + w[1] + w[2] + w[3]) * (1.0f / (float)QOUT_N);
        out[QOUT_N]     = m;   // commitment_loss
        out[QOUT_N + 1] = m;   // codebook_loss
    }
}

extern "C" void kernel_launch(void* const* d_in, const int* in_sizes, int n_in,
                              void* d_out, int out_size, void* d_ws, size_t ws_size,
                              hipStream_t stream)
{
    const float* x  = (const float*)d_in[0];   // [8,64,32,32]
    const float* cb = (const float*)d_in[1];   // [8192,64]
    float* out = (float*)d_out;
    char*  ws  = (char*)d_ws;
    (void)ws_size;

    unsigned short* xS  = (unsigned short*)(ws + WS_XS);
    unsigned short* cbS = (unsigned short*)(ws + WS_CBS);
    float* e2h = (float*)(ws + WS_E2H);
    unsigned long long* packedS = (unsigned long long*)(ws + WS_PACK);
    float* part = (float*)(ws + WS_PART);

    vq_prep_kernel<<<160, 256, 0, stream>>>(x, cb, xS, cbS, e2h);
    vq_argmin_kernel<<<dim3(N_PTS / 256, SPLITS), 256, 0, stream>>>(xS, cbS, e2h, packedS);
    vq_gather_kernel<<<64, 256, 0, stream>>>(x, cb, packedS, out, part);
    vq_final_kernel<<<1, 256, 0, stream>>>(part, out);
}

// Round 5
// 105.323 us; speedup vs baseline: 1.9386x; 1.1042x over previous
//
#include <hip/hip_runtime.h>

// VQVAE quantize.  x: [8,64,32,32] fp32, codebook: [8192,64] fp32.
// d_out (fp32, concat): [0,524288) quant_out | [524288] commit_loss |
//                       [524289] codebook_loss | [524290,532482) indices
//
// argmin via bf16x3 emulated-fp32 MFMA GEMM:
//   v = h + m + l (3 bf16, exact to ~2^-27); dot = hh+hm+mh+hl+lh+mm
//   key = 0.5*e2[k] - dot  (monotone in d2; verified absmax 0 in R4)

#define N_PTS   8192
#define K_CODES 8192
#define C_DIM   64
#define HWSZ    1024
#define QOUT_N  524288
#define SPLITS  16            // codes per split = 512

// ---- workspace layout (bytes) ----
#define WS_XS    0            // u16 [3][8][8192][8]  = 3145728
#define WS_CBS   3145728      // u16 [3][8][8192][8]  = 3145728
#define WS_E2H   6291456      // float [8192]         = 32768
#define WS_PACK  6324224      // u64 [16][8192]       = 1048576
#define WS_PART  7372800      // float [512]

typedef __attribute__((ext_vector_type(8))) short short8;
typedef __attribute__((ext_vector_type(4))) float floatx4;

__device__ __forceinline__ unsigned short bf16_rne(float f) {
    unsigned u = __float_as_uint(f);
    return (unsigned short)((u + 0x7FFFu + ((u >> 16) & 1u)) >> 16);
}
__device__ __forceinline__ float bf16_val(unsigned short h) {
    return __uint_as_float(((unsigned)h) << 16);
}
__device__ __forceinline__ void split3(float v, unsigned short& h,
                                       unsigned short& m, unsigned short& l) {
    h = bf16_rne(v);
    float r1 = v - bf16_val(h);
    m = bf16_rne(r1);
    float r2 = r1 - bf16_val(m);
    l = bf16_rne(r2);
}

// ============================================================
// Kernel A: prep (no LDS, all coalesced).
//  blocks 0..31  : cb split + e2h. 1 row/thread: read 64 contiguous
//                  floats, emit 24 x 16B lane-contiguous stores.
//  blocks 32..95 : x split, block=(b,g). 4 points/thread: 8 coalesced
//                  float4 channel loads, emit 12 x 16B stores.
// Plane layout [p][g][n][8]: 16B per (point|code, c-octet) == one
// MFMA fragment k-group.
// ============================================================
__global__ __launch_bounds__(256)
void vq_prep_kernel(const float* __restrict__ x,
                    const float* __restrict__ cb,
                    unsigned short* __restrict__ xS,
                    unsigned short* __restrict__ cbS,
                    float* __restrict__ e2h)
{
    const int bx  = blockIdx.x;
    const int tid = threadIdx.x;

    if (bx < 32) {                           // ---- cb split + e2h ----
        const int k = bx * 256 + tid;
        const float* row = cb + k * C_DIM;
        float s = 0.0f;
        #pragma unroll
        for (int g = 0; g < 8; ++g) {
            float4 a = *(const float4*)(row + g * 8);
            float4 b = *(const float4*)(row + g * 8 + 4);
            float vv[8] = {a.x, a.y, a.z, a.w, b.x, b.y, b.z, b.w};
            unsigned short h8[8], m8[8], l8[8];
            #pragma unroll
            for (int j = 0; j < 8; ++j) {
                s = fmaf(vv[j], vv[j], s);
                split3(vv[j], h8[j], m8[j], l8[j]);
            }
            *(uint4*)(cbS + ((size_t)(0 * 8 + g) * 8192 + k) * 8) = *(const uint4*)h8;
            *(uint4*)(cbS + ((size_t)(1 * 8 + g) * 8192 + k) * 8) = *(const uint4*)m8;
            *(uint4*)(cbS + ((size_t)(2 * 8 + g) * 8192 + k) * 8) = *(const uint4*)l8;
        }
        e2h[k] = 0.5f * s;
    } else {                                 // ---- x split ----
        const int u = bx - 32;               // 0..63
        const int b = u >> 3, g = u & 7;
        const float* xb = x + (size_t)(b * C_DIM + g * 8) * HWSZ;
        float v[4][8];                       // [j][cq]
        #pragma unroll
        for (int cq = 0; cq < 8; ++cq) {
            float4 t4 = *(const float4*)(xb + cq * HWSZ + tid * 4);
            v[0][cq] = t4.x; v[1][cq] = t4.y; v[2][cq] = t4.z; v[3][cq] = t4.w;
        }
        #pragma unroll
        for (int j = 0; j < 4; ++j) {
            unsigned short h8[8], m8[8], l8[8];
            #pragma unroll
            for (int cq = 0; cq < 8; ++cq)
                split3(v[j][cq], h8[cq], m8[cq], l8[cq]);
            const size_t n = (size_t)b * 1024 + tid * 4 + j;
            *(uint4*)(xS + ((size_t)(0 * 8 + g) * 8192 + n) * 8) = *(const uint4*)h8;
            *(uint4*)(xS + ((size_t)(1 * 8 + g) * 8192 + n) * 8) = *(const uint4*)m8;
            *(uint4*)(xS + ((size_t)(2 * 8 + g) * 8192 + n) * 8) = *(const uint4*)l8;
        }
    }
}

// ============================================================
// Kernel B: argmin via MFMA. grid (32 m-blocks, 16 splits), 256 thr.
// Wave owns 64 points (4 tiles of 16); A-frags in regs (96 VGPR).
// nt-loop unrolled x2 with register double-buffered B-frags so the
// L2 B-frag loads overlap the 48 MFMAs of the other buffer.
// Layouts (verified m89/m91/m120): A[m=lane&15][k=quad*8+j],
// B[k=quad*8+j][n=lane&15], C: col=lane&15, row=quad*4+reg.
// ============================================================
__device__ __forceinline__ void loadB(const unsigned short* __restrict__ cbS,
                                      const float* __restrict__ e2h,
                                      int code, int quad,
                                      short8 bf[3][2], float& e2v)
{
    #pragma unroll
    for (int p = 0; p < 3; ++p)
        #pragma unroll
        for (int s = 0; s < 2; ++s) {
            int g = s * 4 + quad;
            bf[p][s] = *(const short8*)(cbS + ((size_t)(p * 8 + g) * 8192 + code) * 8);
        }
    e2v = e2h[code];
}

__device__ __forceinline__ void computeTile(const short8 af[4][3][2],
                                            const short8 bf[3][2],
                                            float e2v, int code,
                                            float bestk[4][4], int besti[4][4])
{
    floatx4 acc[4];
    #pragma unroll
    for (int t = 0; t < 4; ++t) acc[t] = (floatx4){0.f, 0.f, 0.f, 0.f};

    #pragma unroll
    for (int s = 0; s < 2; ++s) {
        #pragma unroll
        for (int t = 0; t < 4; ++t)
            acc[t] = __builtin_amdgcn_mfma_f32_16x16x32_bf16(af[t][0][s], bf[0][s], acc[t], 0, 0, 0); // hh
        #pragma unroll
        for (int t = 0; t < 4; ++t)
            acc[t] = __builtin_amdgcn_mfma_f32_16x16x32_bf16(af[t][0][s], bf[1][s], acc[t], 0, 0, 0); // hm
        #pragma unroll
        for (int t = 0; t < 4; ++t)
            acc[t] = __builtin_amdgcn_mfma_f32_16x16x32_bf16(af[t][1][s], bf[0][s], acc[t], 0, 0, 0); // mh
        #pragma unroll
        for (int t = 0; t < 4; ++t)
            acc[t] = __builtin_amdgcn_mfma_f32_16x16x32_bf16(af[t][0][s], bf[2][s], acc[t], 0, 0, 0); // hl
        #pragma unroll
        for (int t = 0; t < 4; ++t)
            acc[t] = __builtin_amdgcn_mfma_f32_16x16x32_bf16(af[t][2][s], bf[0][s], acc[t], 0, 0, 0); // lh
        #pragma unroll
        for (int t = 0; t < 4; ++t)
            acc[t] = __builtin_amdgcn_mfma_f32_16x16x32_bf16(af[t][1][s], bf[1][s], acc[t], 0, 0, 0); // mm
    }

    #pragma unroll
    for (int t = 0; t < 4; ++t)
        #pragma unroll
        for (int r = 0; r < 4; ++r) {
            float key = e2v - acc[t][r];
            bool lt = key < bestk[t][r];       // strict: earlier code wins ties
            bestk[t][r] = lt ? key  : bestk[t][r];
            besti[t][r] = lt ? code : besti[t][r];
        }
}

__global__ __launch_bounds__(256, 2)
void vq_argmin_kernel(const unsigned short* __restrict__ xS,
                      const unsigned short* __restrict__ cbS,
                      const float* __restrict__ e2h,
                      unsigned long long* __restrict__ packedS)
{
    __shared__ unsigned long long red[256][17];
    const int tid   = threadIdx.x;
    const int lane  = tid & 63;
    const int w     = tid >> 6;
    const int col   = lane & 15;
    const int quad  = lane >> 4;
    const int mb    = blockIdx.x;
    const int split = blockIdx.y;
    const int m0    = mb * 256 + w * 64;
    const int nb0   = split * 512;

    // A fragments: 4 tiles x 3 planes x 2 ksteps (96 VGPRs)
    short8 af[4][3][2];
    #pragma unroll
    for (int t = 0; t < 4; ++t) {
        int pt = m0 + t * 16 + col;
        #pragma unroll
        for (int p = 0; p < 3; ++p)
            #pragma unroll
            for (int s = 0; s < 2; ++s) {
                int g = s * 4 + quad;
                af[t][p][s] = *(const short8*)(xS + ((size_t)(p * 8 + g) * 8192 + pt) * 8);
            }
    }

    float bestk[4][4];
    int   besti[4][4];
    #pragma unroll
    for (int t = 0; t < 4; ++t)
        #pragma unroll
        for (int r = 0; r < 4; ++r) {
            bestk[t][r] = __uint_as_float(0x7F800000u);  // +inf
            besti[t][r] = 0;
        }

    short8 b0[3][2], b1[3][2];
    float  e0, e1;
    loadB(cbS, e2h, nb0 + col, quad, b0, e0);

    for (int nt = 0; nt < 32; nt += 2) {
        loadB(cbS, e2h, nb0 + (nt + 1) * 16 + col, quad, b1, e1);
        computeTile(af, b0, e0, nb0 + nt * 16 + col, bestk, besti);
        if (nt + 2 < 32)
            loadB(cbS, e2h, nb0 + (nt + 2) * 16 + col, quad, b0, e0);
        computeTile(af, b1, e1, nb0 + (nt + 1) * 16 + col, bestk, besti);
    }

    // pack + cross-col reduce via LDS
    #pragma unroll
    for (int t = 0; t < 4; ++t)
        #pragma unroll
        for (int r = 0; r < 4; ++r) {
            unsigned u = __float_as_uint(bestk[t][r]);
            u = ((int)u < 0) ? ~u : (u | 0x80000000u);
            unsigned long long p = ((unsigned long long)u << 32) | (unsigned)besti[t][r];
            red[w * 64 + t * 16 + quad * 4 + r][col] = p;
        }
    __syncthreads();
    unsigned long long v = red[tid][0];
    #pragma unroll
    for (int c = 1; c < 16; ++c) {
        unsigned long long q = red[tid][c];
        v = (q < v) ? q : v;
    }
    packedS[split * N_PTS + mb * 256 + tid] = v;
}

// ============================================================
// Kernel C: gather. 128 blocks x 256; 4 threads per point (16-ch
// quarters). Reduce the 16 split slots, write quant_out/indices,
// per-wave loss partials (no atomics).
// ============================================================
__global__ __launch_bounds__(256)
void vq_gather_kernel(const float* __restrict__ x,
                      const float* __restrict__ cb,
                      const unsigned long long* __restrict__ packedS,
                      float* __restrict__ out,
                      float* __restrict__ part)
{
    const int t = blockIdx.x * 256 + threadIdx.x;   // 0..32767
    const int n  = t & (N_PTS - 1);
    const int qd = t >> 13;                          // 0..3
    const int c0 = qd * 16;

    unsigned long long v = packedS[n];
    #pragma unroll
    for (int s = 1; s < SPLITS; ++s) {
        unsigned long long q = packedS[s * N_PTS + n];
        v = (q < v) ? q : v;
    }
    const unsigned idx = (unsigned)(v & 0xFFFFFFFFull);

    const int b  = n >> 10;
    const int hw = n & 1023;
    const float* xb = x   + (size_t)b * (C_DIM * HWSZ) + hw;
    float*       ob = out + (size_t)b * (C_DIM * HWSZ) + hw;

    float s = 0.0f;
    #pragma unroll
    for (int c4 = 0; c4 < 4; ++c4) {
        float4 q = *(const float4*)(cb + (size_t)idx * C_DIM + c0 + c4 * 4);
        float qa[4] = {q.x, q.y, q.z, q.w};
        #pragma unroll
        for (int j = 0; j < 4; ++j) {
            int c = c0 + c4 * 4 + j;
            float xv = xb[c * HWSZ];
            float d  = qa[j] - xv;          // quant - x (reference rounding)
            s = fmaf(d, d, s);
            ob[c * HWSZ] = xv + d;          // straight-through: x + (q - x)
        }
    }

    if (qd == 0) out[QOUT_N + 2 + n] = (float)idx;

    #pragma unroll
    for (int off = 32; off > 0; off >>= 1) s += __shfl_down(s, off, 64);
    if ((threadIdx.x & 63) == 0) part[t >> 6] = s;
}

// ============================================================
// Kernel D: final loss reduction (512 partials -> 2 scalars).
// ============================================================
__global__ __launch_bounds__(256)
void vq_final_kernel(const float* __restrict__ part, float* __restrict__ out)
{
    __shared__ float w[4];
    float s = part[threadIdx.x] + part[threadIdx.x + 256];
    #pragma unroll
    for (int off = 32; off > 0; off >>= 1) s += __shfl_down(s, off, 64);
    if ((threadIdx.x & 63) == 0) w[threadIdx.x >> 6] = s;
    __syncthreads();
    if (threadIdx.x == 0) {
        float m = (w[0] + w[1] + w[2] + w[3]) * (1.0f / (float)QOUT_N);
        out[QOUT_N]     = m;   // commitment_loss
        out[QOUT_N + 1] = m;   // codebook_loss
    }
}

extern "C" void kernel_launch(void* const* d_in, const int* in_sizes, int n_in,
                              void* d_out, int out_size, void* d_ws, size_t ws_size,
                              hipStream_t stream)
{
    const float* x  = (const float*)d_in[0];   // [8,64,32,32]
    const float* cb = (const float*)d_in[1];   // [8192,64]
    float* out = (float*)d_out;
    char*  ws  = (char*)d_ws;
    (void)ws_size;

    unsigned short* xS  = (unsigned short*)(ws + WS_XS);
    unsigned short* cbS = (unsigned short*)(ws + WS_CBS);
    float* e2h = (float*)(ws + WS_E2H);
    unsigned long long* packedS = (unsigned long long*)(ws + WS_PACK);
    float* part = (float*)(ws + WS_PART);

    vq_prep_kernel<<<96, 256, 0, stream>>>(x, cb, xS, cbS, e2h);
    vq_argmin_kernel<<<dim3(N_PTS / 256, SPLITS), 256, 0, stream>>>(xS, cbS, e2h, packedS);
    vq_gather_kernel<<<128, 256, 0, stream>>>(x, cb, packedS, out, part);
    vq_final_kernel<<<1, 256, 0, stream>>>(part, out);
}